// Round 1
// baseline (1291.537 us; speedup 1.0000x reference)
//
#include <hip/hip_runtime.h>

// Superpixel mean pooling:
//   x: [B=4, C=128, H=512, W=512] f32, labels: [B, 1, H, W] int32 (values < 512)
//   out: [B, L=512, C=128] f32 = mean of x over pixels sharing a label.
//
// R2: transpose-scheme sum_kernel. Previous version did per-pixel LDS atomics
// with per-lane random labels -> random-bank ds_add_f32 (~200 cy/instr,
// 8.1M bank-conflict cycles, VALUBusy 1%, HBM 5.5%). Now:
//   - stage x in 32ch x 256px LDS tiles via global_load_lds (width 16),
//     with XOR-preswizzled global source (linear LDS dest, m173 pattern)
//   - atomic phase: half-wave = 32 channels of ONE pixel -> acc[l][c],
//     bank = c -> conflict-free atomics, label uniform per half-wave
//   - acc layout [label][channel] (64 KB), tile 32 KB, labels 1 KB = 97 KB LDS

constexpr int Bn = 4, Cn = 128, Hn = 512, Wn = 512;
constexpr int Pn = Hn * Wn;        // 262144 pixels per image
constexpr int Ln = 512;            // labels
constexpr int CPB = 32;            // channels per block
constexpr int CG = Cn / CPB;       // 4 channel groups
constexpr int SPLITS = 16;         // pixel splits per (b, cg) -> 256 blocks total
constexpr int NPIX = Pn / SPLITS;  // 16384 pixels per block
constexpr int TP = 256;            // pixels per LDS tile
constexpr int NT = NPIX / TP;      // 64 tiles per block
constexpr int CB = 64;             // count blocks per batch (256 total)

// async global -> LDS, 16 B per lane (lane l writes ldst + 16*l)
#define GLD_LDS16(gsrc, ldst)                                        \
    __builtin_amdgcn_global_load_lds(                                \
        (const __attribute__((address_space(1))) void*)(gsrc),       \
        (__attribute__((address_space(3))) void*)(ldst), 16, 0, 0)

__global__ void zero_kernel(float4* __restrict__ out4, int* __restrict__ counts) {
    const int i = blockIdx.x * 256 + threadIdx.x;   // 65536 threads
    out4[i] = float4{0.f, 0.f, 0.f, 0.f};
    if (i < Bn * Ln) counts[i] = 0;
}

// 64 blocks per batch (256 total -> all CUs), 4096 px each, LDS histogram.
__global__ void count_kernel(const int* __restrict__ labels, int* __restrict__ counts) {
    __shared__ int cnt[Ln];
    const int b   = blockIdx.x >> 6;
    const int blk = blockIdx.x & 63;
    for (int i = threadIdx.x; i < Ln; i += 256) cnt[i] = 0;
    __syncthreads();
    const int4* lab4 = (const int4*)(labels + (size_t)b * Pn + blk * (Pn / CB));
#pragma unroll
    for (int it = 0; it < (Pn / CB) / (4 * 256); ++it) {   // 4 iters
        int4 l = lab4[it * 256 + threadIdx.x];
        atomicAdd(&cnt[l.x], 1);
        atomicAdd(&cnt[l.y], 1);
        atomicAdd(&cnt[l.z], 1);
        atomicAdd(&cnt[l.w], 1);
    }
    __syncthreads();
    for (int i = threadIdx.x; i < Ln; i += 256)
        atomicAdd(&counts[b * Ln + i], cnt[i]);
}

__global__ void __launch_bounds__(256, 1)
sum_kernel(const float* __restrict__ x, const int* __restrict__ labels,
           float* __restrict__ out) {
    // acc[l][c]: float offset l*32 + c -> bank = c -> conflict-free when the
    // 32 lanes of a half-wave carry the 32 channels of one pixel.
    __shared__ float acc[Ln * CPB];   // 64 KB
    // tile row c: 64 float4 slots; slot sl holds global f4 (sl ^ (c&7)).
    // Read of (c, p4) uses slot p4 ^ (c&7): bank-group = ((p4^c7)%8)*4, all 8
    // groups covered across c -> optimal b128 read. Staging keeps LDS linear
    // and permutes the per-lane GLOBAL address instead (same 1 KB/wave burst).
    __shared__ float tile[CPB * TP];  // 32 KB
    __shared__ int   labt[TP];        // 1 KB

    const int bid = blockIdx.x;
    const int ps  = bid & (SPLITS - 1);
    const int cg  = (bid >> 4) & (CG - 1);
    const int b   = bid >> 6;
    const int p0  = ps * NPIX;

    float4* acc4 = (float4*)acc;
    for (int i = threadIdx.x; i < Ln * CPB / 4; i += 256)
        acc4[i] = float4{0.f, 0.f, 0.f, 0.f};

    const int wave = threadIdx.x >> 6;   // 4 waves; wave w stages rows 8w..8w+7
    const int lane = threadIdx.x & 63;

    // Per-row swizzled global source pointers. r = wave*8 + j -> (r & 7) == j.
    const float* src[8];
#pragma unroll
    for (int j = 0; j < 8; ++j) {
        const int r = wave * 8 + j;
        src[j] = x + (size_t)(b * Cn + cg * CPB + r) * Pn + p0 + ((lane ^ j) << 2);
    }
    const int* labsrc = labels + (size_t)b * Pn + p0 + (lane << 2);

    const int c  = lane & 31;            // channel lane
    const int s  = lane >> 5;            // pixel-slot half
    const int c7 = c & 7;
    float* accc  = acc + c;
    const float* trow = tile + c * TP;

    __syncthreads();   // acc zeroed before any atomics

    for (int t = 0; t < NT; ++t) {
        // ---- stage tile t (async, 1 KB per instruction) ----
#pragma unroll
        for (int j = 0; j < 8; ++j)
            GLD_LDS16(src[j] + t * TP, tile + (wave * 8 + j) * TP);
        if (wave == 0)
            GLD_LDS16(labsrc + t * TP, labt);       // 256 ints = 1 KB
        __syncthreads();   // vmcnt drain + barrier -> tile visible to all

        // ---- accumulate: wave w owns tile pixels [64w, 64w+64) ----
#pragma unroll
        for (int k = 0; k < 8; ++k) {
            const int p4 = wave * 16 + k * 2 + s;   // f4 index within row
            const float4 v = *(const float4*)(trow + ((p4 ^ c7) << 2));
            const int4 l4  = *(const int4*)(labt + (p4 << 2));  // uniform/half -> broadcast
            atomicAdd(accc + (l4.x << 5), v.x);     // bank = c, conflict-free
            atomicAdd(accc + (l4.y << 5), v.y);
            atomicAdd(accc + (l4.z << 5), v.z);
            atomicAdd(accc + (l4.w << 5), v.w);
        }
        __syncthreads();   // tile consumed before next staging overwrites it
    }

    // Flush: consecutive lanes -> consecutive c -> LDS conflict-free and
    // global atomics coalesced in 32-float runs. 16 splits contend per out.
    for (int i = threadIdx.x; i < CPB * Ln; i += 256) {
        const int l = i >> 5, cl = i & 31;
        atomicAdd(&out[((size_t)b * Ln + l) * Cn + cg * CPB + cl],
                  acc[(l << 5) + cl]);
    }
}

__global__ void div_kernel(float4* __restrict__ out4, const int* __restrict__ counts) {
    const int i = blockIdx.x * 256 + threadIdx.x;   // 65536 float4s
    const int bl = i >> 5;                          // 32 float4 per (b,l)
    const float inv = 1.0f / fmaxf((float)counts[bl], 1.0f);
    float4 v = out4[i];
    v.x *= inv; v.y *= inv; v.z *= inv; v.w *= inv;
    out4[i] = v;
}

extern "C" void kernel_launch(void* const* d_in, const int* in_sizes, int n_in,
                              void* d_out, int out_size, void* d_ws, size_t ws_size,
                              hipStream_t stream) {
    const float* x      = (const float*)d_in[0];
    const int*   labels = (const int*)d_in[1];
    float* out  = (float*)d_out;
    int* counts = (int*)d_ws;   // 4*512 ints = 8 KB

    zero_kernel <<<(Bn * Ln * Cn / 4) / 256, 256, 0, stream>>>((float4*)out, counts);
    count_kernel<<<Bn * CB,                  256, 0, stream>>>(labels, counts);
    sum_kernel  <<<Bn * CG * SPLITS,         256, 0, stream>>>(x, labels, out);
    div_kernel  <<<(Bn * Ln * Cn / 4) / 256, 256, 0, stream>>>((float4*)out, counts);
}

// Round 2
// 1214.265 us; speedup vs baseline: 1.0636x; 1.0636x over previous
//
#include <hip/hip_runtime.h>

// Superpixel mean pooling:
//   x: [B=4, C=128, H=512, W=512] f32, labels: [B, 1, H, W] int32 (values < 512)
//   out: [B, L=512, C=128] f32 = mean of x over pixels sharing a label.
//
// R3: back to the R1 structure (direct coalesced loads + LDS scatter-add,
// 2 blocks/CU, no staging barriers) but with unsafeAtomicAdd.
// Diagnosis: R1 and R2 both spent ~200 cy per LDS f32 atomic instruction
// (8192/CU in both), independent of bank conflicts, all pipes idle ->
// HIP's default f32 atomicAdd lowering is a CAS loop (denormal-safe).
// unsafeAtomicAdd emits native ds_add_f32 / global_atomic_add_f32 (noret).

constexpr int Bn = 4, Cn = 128, Hn = 512, Wn = 512;
constexpr int Pn = Hn * Wn;        // 262144 pixels per image
constexpr int Ln = 512;            // labels
constexpr int CPB = 32;            // channels per block
constexpr int CG = Cn / CPB;       // 4 channel groups
constexpr int SPLITS = 32;         // pixel splits per (b, cg) -> 512 blocks, 2/CU
constexpr int NPIX = Pn / SPLITS;  // 8192 pixels per block
constexpr int CPW = 8;             // channels per wave (4 waves * 8 = 32)
constexpr int CB = 64;             // count blocks per batch (256 total)

__global__ void zero_kernel(float4* __restrict__ out4, int* __restrict__ counts) {
    const int i = blockIdx.x * 256 + threadIdx.x;   // 65536 threads
    out4[i] = float4{0.f, 0.f, 0.f, 0.f};
    if (i < Bn * Ln) counts[i] = 0;
}

// 64 blocks per batch (256 total -> all CUs), 4096 px each, LDS histogram.
// Int atomics are native hardware ops already.
__global__ void count_kernel(const int* __restrict__ labels, int* __restrict__ counts) {
    __shared__ int cnt[Ln];
    const int b   = blockIdx.x >> 6;
    const int blk = blockIdx.x & 63;
    for (int i = threadIdx.x; i < Ln; i += 256) cnt[i] = 0;
    __syncthreads();
    const int4* lab4 = (const int4*)(labels + (size_t)b * Pn + blk * (Pn / CB));
#pragma unroll
    for (int it = 0; it < (Pn / CB) / (4 * 256); ++it) {   // 4 iters
        int4 l = lab4[it * 256 + threadIdx.x];
        atomicAdd(&cnt[l.x], 1);
        atomicAdd(&cnt[l.y], 1);
        atomicAdd(&cnt[l.z], 1);
        atomicAdd(&cnt[l.w], 1);
    }
    __syncthreads();
    for (int i = threadIdx.x; i < Ln; i += 256)
        atomicAdd(&counts[b * Ln + i], cnt[i]);
}

__global__ void __launch_bounds__(256, 2)
sum_kernel(const float* __restrict__ x, const int* __restrict__ labels,
           float* __restrict__ out) {
    // acc[c_local][label] — 32*512*4 = 64 KB (2 blocks/CU of the 160 KB pool).
    __shared__ float acc[CPB * Ln];

    const int bid = blockIdx.x;
    const int ps  = bid & (SPLITS - 1);
    const int cg  = (bid >> 5) & (CG - 1);
    const int b   = bid >> 7;

    for (int i = threadIdx.x; i < CPB * Ln; i += 256) acc[i] = 0.f;
    __syncthreads();

    const int wave = threadIdx.x >> 6;   // 4 waves per block
    const int lane = threadIdx.x & 63;
    const int p0   = ps * NPIX;

    const int4* lab4 = (const int4*)(labels + (size_t)b * Pn + p0);
    const float4* xp[CPW];
    float* accl[CPW];
#pragma unroll
    for (int j = 0; j < CPW; ++j) {
        const int c_local = wave * CPW + j;        // 4 waves x 8 = 32 channels
        xp[j]   = (const float4*)(x + (size_t)(b * Cn + cg * CPB + c_local) * Pn + p0);
        accl[j] = acc + c_local * Ln;
    }

    for (int it = 0; it < NPIX / (64 * 4); ++it) {  // 32 iters; each wave walks all 8192 px
        const int idx = it * 64 + lane;             // coalesced float4/int4
        const int4 l = lab4[idx];
#pragma unroll
        for (int j = 0; j < CPW; ++j) {
            const float4 v = xp[j][idx];
            unsafeAtomicAdd(&accl[j][l.x], v.x);    // native ds_add_f32 (noret)
            unsafeAtomicAdd(&accl[j][l.y], v.y);
            unsafeAtomicAdd(&accl[j][l.z], v.z);
            unsafeAtomicAdd(&accl[j][l.w], v.w);
        }
    }
    __syncthreads();

    // Flush: i -> (l = i>>5, c_local = i&31) so global atomics are 32
    // consecutive floats per l (coalesced). Native global_atomic_add_f32:
    // fire-and-forget, no CAS retry storms across the 32 contending splits.
    for (int i = threadIdx.x; i < CPB * Ln; i += 256) {
        const int l = i >> 5;
        const int c_local = i & 31;
        unsafeAtomicAdd(&out[((size_t)b * Ln + l) * Cn + cg * CPB + c_local],
                        acc[c_local * Ln + l]);
    }
}

__global__ void div_kernel(float4* __restrict__ out4, const int* __restrict__ counts) {
    const int i = blockIdx.x * 256 + threadIdx.x;   // 65536 float4s
    const int bl = i >> 5;                          // 32 float4 per (b,l)
    const float inv = 1.0f / fmaxf((float)counts[bl], 1.0f);
    float4 v = out4[i];
    v.x *= inv; v.y *= inv; v.z *= inv; v.w *= inv;
    out4[i] = v;
}

extern "C" void kernel_launch(void* const* d_in, const int* in_sizes, int n_in,
                              void* d_out, int out_size, void* d_ws, size_t ws_size,
                              hipStream_t stream) {
    const float* x      = (const float*)d_in[0];
    const int*   labels = (const int*)d_in[1];
    float* out  = (float*)d_out;
    int* counts = (int*)d_ws;   // 4*512 ints = 8 KB

    zero_kernel <<<(Bn * Ln * Cn / 4) / 256, 256, 0, stream>>>((float4*)out, counts);
    count_kernel<<<Bn * CB,                  256, 0, stream>>>(labels, counts);
    sum_kernel  <<<Bn * CG * SPLITS,         256, 0, stream>>>(x, labels, out);
    div_kernel  <<<(Bn * Ln * Cn / 4) / 256, 256, 0, stream>>>((float4*)out, counts);
}